// Round 2
// baseline (316.973 us; speedup 1.0000x reference)
//
#include <hip/hip_runtime.h>
#include <hip/hip_bf16.h>

#define T_TOTAL 1000
#define B_TOTAL 128
#define F_TOTAL 2048
#define C_OUT   10
#define NEUR    (B_TOTAL * C_OUT)   // 1280

#define KSTEPS  (F_TOTAL / 32)      // 64 k-steps of 32
#define NBFRAG  (KSTEPS * 3 * 64)   // 12288 16-byte B fragments (hi/mid/lo)

// bitmask geometry: 1 bit per x element; one 16B chunk = 128 consecutive
// elements stored as {bx (even elems), by (odd elems)} u64 pair.
#define NELEM     (B_TOTAL * T_TOTAL * F_TOTAL)   // 262,144,000
#define NBITCHUNK (NELEM / 128)                   // 2,048,000 16B chunks
#define CITERS    (NBITCHUNK / 4)                 // 512,000 wave-iters (4 chunks each)

typedef __attribute__((ext_vector_type(8))) short bf16x8;
typedef __attribute__((ext_vector_type(4))) float f32x4;

// ---------------------------------------------------------------------------
// Prep: split W exactly into three bf16 terms (W == hi+mid+lo in fp32) and
// store them frag-ordered: fragment idx = (s*3+p)*64 + lane, lane = 16g+r
// holds B[k = s*32 + 8g + j][col r], j=0..7 packed ascending.
// ---------------------------------------------------------------------------
__global__ __launch_bounds__(256) void snn_prep(const float* __restrict__ W,
                                                uint4* __restrict__ bfrag)
{
    const int idx = blockIdx.x * 256 + threadIdx.x;
    if (idx >= NBFRAG) return;
    const int l = idx & 63;
    const int sp = idx >> 6;
    const int p = sp % 3;            // split: 0=hi 1=mid 2=lo
    const int s = sp / 3;            // k-step
    const int g = l >> 4, r = l & 15;
    unsigned out[4] = {0u, 0u, 0u, 0u};
#pragma unroll
    for (int j = 0; j < 8; ++j) {
        const int k = s * 32 + g * 8 + j;
        const float wv = (r < C_OUT) ? W[k * C_OUT + r] : 0.f;
        __hip_bfloat16 bh = __float2bfloat16(wv);
        const float fh = __bfloat162float(bh);
        __hip_bfloat16 bm = __float2bfloat16(wv - fh);
        const float fm = __bfloat162float(bm);
        __hip_bfloat16 bl = __float2bfloat16(wv - fh - fm);   // exact residual
        __hip_bfloat16 sel = (p == 0) ? bh : (p == 1) ? bm : bl;
        const unsigned short bits = *reinterpret_cast<unsigned short*>(&sel);
        out[j >> 1] |= (unsigned)bits << (16 * (j & 1));
    }
    bfrag[idx] = make_uint4(out[0], out[1], out[2], out[3]);
}

// ---------------------------------------------------------------------------
// Compress: x (fp32 {0,1}, 1.05 GB) -> bitmask (33 MB). Pure streaming:
// each wave-iter reads 4 x float2/lane (512 B/instr contiguous, 2 KB total)
// and emits 4 chunks via __ballot. bx bit i = element base+2i, by = odds.
// This is the m13-proven linear pattern -> should run at ~6.3 TB/s, unlike
// the scattered 16-row MFMA A-load pattern (~4 TB/s measured).
// ---------------------------------------------------------------------------
__global__ __launch_bounds__(256) void snn_compress(const float* __restrict__ x,
                                                    uint4* __restrict__ bits)
{
    const int lane = threadIdx.x & 63;
    const int w    = threadIdx.x >> 6;
    const size_t wave_id = (size_t)blockIdx.x * 4 + w;
    const size_t nwaves  = (size_t)gridDim.x * 4;

    for (size_t it = wave_id; it < CITERS; it += nwaves) {
        const float* __restrict__ p = x + it * 512;
#pragma unroll
        for (int q = 0; q < 4; ++q) {
            const float2 v = *reinterpret_cast<const float2*>(p + q * 128 + 2 * lane);
            const unsigned long long bx = __ballot(v.x != 0.f);
            const unsigned long long by = __ballot(v.y != 0.f);
            if (lane == 0) {
                uint4 o;
                o.x = (unsigned)bx; o.y = (unsigned)(bx >> 32);
                o.z = (unsigned)by; o.w = (unsigned)(by >> 32);
                bits[it * 4 + q] = o;
            }
        }
    }
}

// ---------------------------------------------------------------------------
// Phase 1 (MFMA from bits): I[b*10+c][t] = x[b,t,:] @ W[:,c], 3 bf16 splits.
// A-operand rebuilt in-register from the bitmask: per chunk (128 k-bits,
// 4 k-steps) each lane loads one 16B bit-chunk for its row (4x address
// replication across g is HW-merged). Expansion: bf16 1.0 = 0x3F80; packed
// pair u[j] = (sext(bit even)&0x3F80) | (sext(bit odd)&0x3F800000).
// HBM traffic: 33 MB bits + 786 MB B-frags from L2/L3 -> compute-bound.
// ---------------------------------------------------------------------------
__device__ __forceinline__ unsigned sext_bit(unsigned wrd, int pos)
{
#if __has_builtin(__builtin_amdgcn_sbfe)
    return (unsigned)__builtin_amdgcn_sbfe((int)wrd, pos, 1);
#else
    return (unsigned)(((int)(wrd << (31 - pos))) >> 31);
#endif
}

__global__ __launch_bounds__(256) void snn_phase1_bits(
    const uint4* __restrict__ bits, const uint4* __restrict__ bfrag,
    float* __restrict__ Ibuf, int t0, int cur)
{
    const int b  = blockIdx.y;
    const int w  = threadIdx.x >> 6;
    const int l  = threadIdx.x & 63;
    const int r  = l & 15, g = l >> 4;
    const int ttbase = blockIdx.x * 128 + w * 32;  // wave's 32-row tile (local t)

    int t_row0 = t0 + ttbase + r;
    int t_row1 = t_row0 + 16;
    if (t_row0 > T_TOTAL - 1) t_row0 = T_TOTAL - 1;
    if (t_row1 > T_TOTAL - 1) t_row1 = T_TOTAL - 1;
    // 16 bit-chunks per row (2048 bits).
    const uint4* __restrict__ ap0 = bits + (size_t)(b * T_TOTAL + t_row0) * 16;
    const uint4* __restrict__ ap1 = bits + (size_t)(b * T_TOTAL + t_row1) * 16;

    f32x4 acc0 = {0.f, 0.f, 0.f, 0.f};
    f32x4 acc1 = {0.f, 0.f, 0.f, 0.f};
    const uint4* __restrict__ bp = bfrag + l;

    const int g4 = 4 * g;            // per-lane bit-position base

    uint4 cA0 = ap0[0];
    uint4 cA1 = ap1[0];

#pragma unroll 1
    for (int c = 0; c < 16; ++c) {
        // prefetch next chunk (clamped dup on last iter; branch-free)
        const int cn = (c < 15) ? c + 1 : 15;
        const uint4 nA0 = ap0[cn];
        const uint4 nA1 = ap1[cn];

#pragma unroll
        for (int ss = 0; ss < 4; ++ss) {
            const int s = c * 4 + ss;
            union { bf16x8 v; uint4 q; } q0, q1, q2;
            q0.q = bp[(s * 3 + 0) * 64];
            q1.q = bp[(s * 3 + 1) * 64];
            q2.q = bp[(s * 3 + 2) * 64];

            const unsigned ew0 = (ss < 2) ? cA0.x : cA0.y;  // even elems, tile0
            const unsigned ow0 = (ss < 2) ? cA0.z : cA0.w;  // odd  elems, tile0
            const unsigned ew1 = (ss < 2) ? cA1.x : cA1.y;
            const unsigned ow1 = (ss < 2) ? cA1.z : cA1.w;

            union { bf16x8 v; unsigned u[4]; } af0, af1;
#pragma unroll
            for (int j = 0; j < 4; ++j) {
                const int pos = (ss & 1) * 16 + g4 + j;   // bit position, static offsets
                af0.u[j] = (sext_bit(ew0, pos) & 0x3F80u) |
                           (sext_bit(ow0, pos) & 0x3F800000u);
                af1.u[j] = (sext_bit(ew1, pos) & 0x3F80u) |
                           (sext_bit(ow1, pos) & 0x3F800000u);
            }

            acc0 = __builtin_amdgcn_mfma_f32_16x16x32_bf16(af0.v, q0.v, acc0, 0, 0, 0);
            acc1 = __builtin_amdgcn_mfma_f32_16x16x32_bf16(af1.v, q0.v, acc1, 0, 0, 0);
            acc0 = __builtin_amdgcn_mfma_f32_16x16x32_bf16(af0.v, q1.v, acc0, 0, 0, 0);
            acc1 = __builtin_amdgcn_mfma_f32_16x16x32_bf16(af1.v, q1.v, acc1, 0, 0, 0);
            acc0 = __builtin_amdgcn_mfma_f32_16x16x32_bf16(af0.v, q2.v, acc0, 0, 0, 0);
            acc1 = __builtin_amdgcn_mfma_f32_16x16x32_bf16(af1.v, q2.v, acc1, 0, 0, 0);
        }
        cA0 = nA0; cA1 = nA1;
    }

    // C/D layout (m89): col = l&15, row = 4*(l>>4) + reg. Rows are t.
    const int tt4_0 = ttbase + 4 * g;
    const int tt4_1 = tt4_0 + 16;
    if (r < C_OUT) {
        if (tt4_0 + 3 < cur) {
            const float4 v = make_float4(acc0[0], acc0[1], acc0[2], acc0[3]);
            *reinterpret_cast<float4*>(&Ibuf[((size_t)b * C_OUT + r) * cur + tt4_0]) = v;
        }
        if (tt4_1 + 3 < cur) {
            const float4 v = make_float4(acc1[0], acc1[1], acc1[2], acc1[3]);
            *reinterpret_cast<float4*>(&Ibuf[((size_t)b * C_OUT + r) * cur + tt4_1]) = v;
        }
    }
}

// ---------------------------------------------------------------------------
// Phase 2: per-neuron LIF scan, exact reference semantics (unchanged).
// ---------------------------------------------------------------------------
__device__ __forceinline__ void snn_step(float Iv, float& V, float& refr, float& cnt)
{
    const bool act = (refr <= 0.f);
    V += act ? Iv : 0.f;
    const bool fired = act && ((V - 0.4f) > 0.f);
    cnt += fired ? 1.f : 0.f;
    V    = fired ? 0.f : V;
    refr = fired ? 3.f : refr;
    refr = fmaxf(refr - 1.f, 0.f);
}

__global__ __launch_bounds__(256) void snn_phase2(
    const float* __restrict__ Ibuf, float* __restrict__ state,
    float* __restrict__ out, int t0, int Tc, int last)
{
    const int n = blockIdx.x * 256 + threadIdx.x;
    if (n >= NEUR) return;

    float V, refr, cnt;
    if (t0 == 0) { V = 0.f; refr = 0.f; cnt = 0.f; }
    else { V = state[n]; refr = state[NEUR + n]; cnt = state[2 * NEUR + n]; }

    const float* __restrict__ I = Ibuf + (size_t)n * Tc;

    int i = 0;
    for (; i + 16 <= Tc; i += 16) {
        const float4 a = *reinterpret_cast<const float4*>(I + i);
        const float4 b = *reinterpret_cast<const float4*>(I + i + 4);
        const float4 c = *reinterpret_cast<const float4*>(I + i + 8);
        const float4 d = *reinterpret_cast<const float4*>(I + i + 12);
        snn_step(a.x, V, refr, cnt); snn_step(a.y, V, refr, cnt);
        snn_step(a.z, V, refr, cnt); snn_step(a.w, V, refr, cnt);
        snn_step(b.x, V, refr, cnt); snn_step(b.y, V, refr, cnt);
        snn_step(b.z, V, refr, cnt); snn_step(b.w, V, refr, cnt);
        snn_step(c.x, V, refr, cnt); snn_step(c.y, V, refr, cnt);
        snn_step(c.z, V, refr, cnt); snn_step(c.w, V, refr, cnt);
        snn_step(d.x, V, refr, cnt); snn_step(d.y, V, refr, cnt);
        snn_step(d.z, V, refr, cnt); snn_step(d.w, V, refr, cnt);
    }
    for (; i < Tc; ++i) snn_step(I[i], V, refr, cnt);

    if (last) {
        out[n] = cnt;
    } else {
        state[n] = V; state[NEUR + n] = refr; state[2 * NEUR + n] = cnt;
    }
}

// ---------------------------------------------------------------------------
extern "C" void kernel_launch(void* const* d_in, const int* in_sizes, int n_in,
                              void* d_out, int out_size, void* d_ws, size_t ws_size,
                              hipStream_t stream)
{
    const float* x = (const float*)d_in[0];   // [128, 1000, 2048] fp32 {0,1}
    const float* W = (const float*)d_in[1];   // [2048, 10] fp32
    float* out = (float*)d_out;               // [128, 10] fp32

    // ws layout: state (15360 B) | bfrag (196608 B) | bits (32.768 MB) | Ibuf
    float* state = (float*)d_ws;
    uint4* bfrag = (uint4*)((char*)d_ws + 3 * NEUR * sizeof(float));
    uint4* bits  = (uint4*)((char*)d_ws + 3 * NEUR * sizeof(float) + NBFRAG * 16);
    float* Ibuf  = (float*)((char*)d_ws + 3 * NEUR * sizeof(float) + NBFRAG * 16
                            + (size_t)NBITCHUNK * 16);

    snn_prep<<<(NBFRAG + 255) / 256, 256, 0, stream>>>(W, bfrag);
    snn_compress<<<2048, 256, 0, stream>>>(x, bits);

    // Chunk T so Ibuf fits the workspace (single chunk at ws ~4 GB).
    const size_t head = 3 * NEUR + NBFRAG * 4 + (size_t)NBITCHUNK * 4;  // floats
    const size_t ws_floats = ws_size / sizeof(float);
    long avail = (long)ws_floats - (long)head;
    int Tc = (avail > 0) ? (int)(avail / NEUR) : 0;
    if (Tc > T_TOTAL) Tc = T_TOTAL;
    Tc &= ~3;
    if (Tc <= 0) Tc = 4;

    for (int t0 = 0; t0 < T_TOTAL; t0 += Tc) {
        int cur = T_TOTAL - t0; if (cur > Tc) cur = Tc;
        dim3 g1((cur + 127) / 128, B_TOTAL, 1);
        snn_phase1_bits<<<g1, 256, 0, stream>>>(bits, bfrag, Ibuf, t0, cur);
        const int last = (t0 + cur >= T_TOTAL) ? 1 : 0;
        snn_phase2<<<(NEUR + 255) / 256, 256, 0, stream>>>(Ibuf, state, out, t0, cur, last);
    }
}

// Round 3
// 303.413 us; speedup vs baseline: 1.0447x; 1.0447x over previous
//
#include <hip/hip_runtime.h>
#include <hip/hip_bf16.h>

#define T_TOTAL 1000
#define B_TOTAL 128
#define F_TOTAL 2048
#define C_OUT   10
#define NEUR    (B_TOTAL * C_OUT)   // 1280

#define KSTEPS  (F_TOTAL / 32)      // 64 k-steps of 32
#define NBFRAG  (KSTEPS * 3 * 64)   // 12288 16-byte B fragments (hi/mid/lo)

// bitmask geometry v2 (ballot-native): 256-elem group -> 32 B.
//   lane i of compress loads float4 (elems 4i..4i+3); w[c] = ballot(v[c]!=0)
//   => bit i of w[c] = x[G*256 + 4i + c].
//   stored: uint4 A = {w0.lo, w0.hi, w1.lo, w1.hi}, uint4 B = {w2.lo, w2.hi, w3.lo, w3.hi}
#define NELEM     (B_TOTAL * T_TOTAL * F_TOTAL)   // 262,144,000
#define NGROUP    (NELEM / 256)                   // 1,024,000 groups
#define NBITU4    (NGROUP * 2)                    // 2,048,000 uint4 = 32.768 MB
#define CITERS    (NGROUP / 4)                    // 256,000 wave-iters (4 groups each)

typedef __attribute__((ext_vector_type(8))) short bf16x8;
typedef __attribute__((ext_vector_type(4))) float f32x4;

// ---------------------------------------------------------------------------
// Prep: split W exactly into three bf16 terms (W == hi+mid+lo in fp32),
// frag-ordered: fragment idx = (s*3+p)*64 + lane, lane = 16g+r holds
// B[k = s*32 + 8g + j][col r], j=0..7 packed ascending.
// ---------------------------------------------------------------------------
__global__ __launch_bounds__(256) void snn_prep(const float* __restrict__ W,
                                                uint4* __restrict__ bfrag)
{
    const int idx = blockIdx.x * 256 + threadIdx.x;
    if (idx >= NBFRAG) return;
    const int l = idx & 63;
    const int sp = idx >> 6;
    const int p = sp % 3;            // split: 0=hi 1=mid 2=lo
    const int s = sp / 3;            // k-step
    const int g = l >> 4, r = l & 15;
    unsigned out[4] = {0u, 0u, 0u, 0u};
#pragma unroll
    for (int j = 0; j < 8; ++j) {
        const int k = s * 32 + g * 8 + j;
        const float wv = (r < C_OUT) ? W[k * C_OUT + r] : 0.f;
        __hip_bfloat16 bh = __float2bfloat16(wv);
        const float fh = __bfloat162float(bh);
        __hip_bfloat16 bm = __float2bfloat16(wv - fh);
        const float fm = __bfloat162float(bm);
        __hip_bfloat16 bl = __float2bfloat16(wv - fh - fm);   // exact residual
        __hip_bfloat16 sel = (p == 0) ? bh : (p == 1) ? bm : bl;
        const unsigned short bits = *reinterpret_cast<unsigned short*>(&sel);
        out[j >> 1] |= (unsigned)bits << (16 * (j & 1));
    }
    bfrag[idx] = make_uint4(out[0], out[1], out[2], out[3]);
}

// ---------------------------------------------------------------------------
// Compress v2: x (fp32 {0,1}, 1.05 GB) -> 32.8 MB bitmask. m13-proven width:
// 4 independent float4 loads (16 B/lane, 1 KB/instr, 4 KB per wave-iter in
// flight), then 16 ballots, then lane0 stores 128 B. Per CU: 32 waves x 4 KB
// = 128 KB outstanding >> latency-BW product.
// ---------------------------------------------------------------------------
__global__ __launch_bounds__(256) void snn_compress(const float* __restrict__ x,
                                                    uint4* __restrict__ bits)
{
    const int lane = threadIdx.x & 63;
    const int w    = threadIdx.x >> 6;
    const size_t wave_id = (size_t)blockIdx.x * 4 + w;
    const size_t nwaves  = (size_t)gridDim.x * 4;

    for (size_t it = wave_id; it < CITERS; it += nwaves) {
        const float* __restrict__ p = x + it * 1024 + 4 * lane;
        const float4 v0 = *reinterpret_cast<const float4*>(p);
        const float4 v1 = *reinterpret_cast<const float4*>(p + 256);
        const float4 v2 = *reinterpret_cast<const float4*>(p + 512);
        const float4 v3 = *reinterpret_cast<const float4*>(p + 768);

        const unsigned long long b00 = __ballot(v0.x != 0.f);
        const unsigned long long b01 = __ballot(v0.y != 0.f);
        const unsigned long long b02 = __ballot(v0.z != 0.f);
        const unsigned long long b03 = __ballot(v0.w != 0.f);
        const unsigned long long b10 = __ballot(v1.x != 0.f);
        const unsigned long long b11 = __ballot(v1.y != 0.f);
        const unsigned long long b12 = __ballot(v1.z != 0.f);
        const unsigned long long b13 = __ballot(v1.w != 0.f);
        const unsigned long long b20 = __ballot(v2.x != 0.f);
        const unsigned long long b21 = __ballot(v2.y != 0.f);
        const unsigned long long b22 = __ballot(v2.z != 0.f);
        const unsigned long long b23 = __ballot(v2.w != 0.f);
        const unsigned long long b30 = __ballot(v3.x != 0.f);
        const unsigned long long b31 = __ballot(v3.y != 0.f);
        const unsigned long long b32 = __ballot(v3.z != 0.f);
        const unsigned long long b33 = __ballot(v3.w != 0.f);

        if (lane == 0) {
            uint4* __restrict__ o = bits + it * 8;
            o[0] = make_uint4((unsigned)b00, (unsigned)(b00 >> 32),
                              (unsigned)b01, (unsigned)(b01 >> 32));
            o[1] = make_uint4((unsigned)b02, (unsigned)(b02 >> 32),
                              (unsigned)b03, (unsigned)(b03 >> 32));
            o[2] = make_uint4((unsigned)b10, (unsigned)(b10 >> 32),
                              (unsigned)b11, (unsigned)(b11 >> 32));
            o[3] = make_uint4((unsigned)b12, (unsigned)(b12 >> 32),
                              (unsigned)b13, (unsigned)(b13 >> 32));
            o[4] = make_uint4((unsigned)b20, (unsigned)(b20 >> 32),
                              (unsigned)b21, (unsigned)(b21 >> 32));
            o[5] = make_uint4((unsigned)b22, (unsigned)(b22 >> 32),
                              (unsigned)b23, (unsigned)(b23 >> 32));
            o[6] = make_uint4((unsigned)b30, (unsigned)(b30 >> 32),
                              (unsigned)b31, (unsigned)(b31 >> 32));
            o[7] = make_uint4((unsigned)b32, (unsigned)(b32 >> 32),
                              (unsigned)b33, (unsigned)(b33 >> 32));
        }
    }
}

// ---------------------------------------------------------------------------
// Phase 1 (MFMA from bits v2). Per group (256 k, 8 k-steps), lane loads the
// row's 32 B {A,B} words. For step ss, lane (r,g), packed pair u[j]:
//   even elem = 32ss+8g+2j -> word w0 (j even) / w2 (j odd), bit 8(ss&3)+2g+(j>>1)
//   odd  elem = +1         -> word w1 (j even) / w3 (j odd), same bit
//   hi/lo u32 of the u64 selected by ss<4. Verified at corners (g,ss,j).
// ---------------------------------------------------------------------------
__device__ __forceinline__ unsigned sext_bit(unsigned wrd, int pos)
{
#if __has_builtin(__builtin_amdgcn_sbfe)
    return (unsigned)__builtin_amdgcn_sbfe((int)wrd, pos, 1);
#else
    return (unsigned)(((int)(wrd << (31 - pos))) >> 31);
#endif
}

#define EXPAND(Aa, Ab, AF)                                                        \
    {                                                                             \
        const unsigned w0 = (ss < 4) ? Aa.x : Aa.y;                               \
        const unsigned w1 = (ss < 4) ? Aa.z : Aa.w;                               \
        const unsigned w2 = (ss < 4) ? Ab.x : Ab.y;                               \
        const unsigned w3 = (ss < 4) ? Ab.z : Ab.w;                               \
        AF.u[0] = (sext_bit(w0, p0) & 0x3F80u) | (sext_bit(w1, p0) & 0x3F800000u); \
        AF.u[1] = (sext_bit(w2, p0) & 0x3F80u) | (sext_bit(w3, p0) & 0x3F800000u); \
        AF.u[2] = (sext_bit(w0, p1) & 0x3F80u) | (sext_bit(w1, p1) & 0x3F800000u); \
        AF.u[3] = (sext_bit(w2, p1) & 0x3F80u) | (sext_bit(w3, p1) & 0x3F800000u); \
    }

__global__ __launch_bounds__(256) void snn_phase1_bits(
    const uint4* __restrict__ bits, const uint4* __restrict__ bfrag,
    float* __restrict__ Ibuf, int t0, int cur)
{
    const int b  = blockIdx.y;
    const int w  = threadIdx.x >> 6;
    const int l  = threadIdx.x & 63;
    const int r  = l & 15, g = l >> 4;
    const int ttbase = blockIdx.x * 128 + w * 32;  // wave's 32-row tile (local t)

    int t_row0 = t0 + ttbase + r;
    int t_row1 = t_row0 + 16;
    if (t_row0 > T_TOTAL - 1) t_row0 = T_TOTAL - 1;
    if (t_row1 > T_TOTAL - 1) t_row1 = T_TOTAL - 1;
    // 8 groups per row (2048 elems) -> 16 uint4 per row.
    const uint4* __restrict__ ap0 = bits + (size_t)(b * T_TOTAL + t_row0) * 16;
    const uint4* __restrict__ ap1 = bits + (size_t)(b * T_TOTAL + t_row1) * 16;

    f32x4 acc0 = {0.f, 0.f, 0.f, 0.f};
    f32x4 acc1 = {0.f, 0.f, 0.f, 0.f};
    const uint4* __restrict__ bp = bfrag + l;

    const int g2 = 2 * g;            // per-lane bit-position base

    uint4 cA0a = ap0[0], cA0b = ap0[1];
    uint4 cA1a = ap1[0], cA1b = ap1[1];

#pragma unroll 1
    for (int gi = 0; gi < 8; ++gi) {
        // prefetch next group's words (clamped dup on last iter)
        const int gn = (gi < 7) ? gi + 1 : 7;
        const uint4 nA0a = ap0[gn * 2], nA0b = ap0[gn * 2 + 1];
        const uint4 nA1a = ap1[gn * 2], nA1b = ap1[gn * 2 + 1];

#pragma unroll
        for (int ss = 0; ss < 8; ++ss) {
            const int s = gi * 8 + ss;
            union { bf16x8 v; uint4 q; } q0, q1, q2;
            q0.q = bp[(s * 3 + 0) * 64];
            q1.q = bp[(s * 3 + 1) * 64];
            q2.q = bp[(s * 3 + 2) * 64];

            const int p0 = g2 + 8 * (ss & 3);   // compile-time const + 2g
            const int p1 = p0 + 1;

            union { bf16x8 v; unsigned u[4]; } af0, af1;
            EXPAND(cA0a, cA0b, af0)
            EXPAND(cA1a, cA1b, af1)

            acc0 = __builtin_amdgcn_mfma_f32_16x16x32_bf16(af0.v, q0.v, acc0, 0, 0, 0);
            acc1 = __builtin_amdgcn_mfma_f32_16x16x32_bf16(af1.v, q0.v, acc1, 0, 0, 0);
            acc0 = __builtin_amdgcn_mfma_f32_16x16x32_bf16(af0.v, q1.v, acc0, 0, 0, 0);
            acc1 = __builtin_amdgcn_mfma_f32_16x16x32_bf16(af1.v, q1.v, acc1, 0, 0, 0);
            acc0 = __builtin_amdgcn_mfma_f32_16x16x32_bf16(af0.v, q2.v, acc0, 0, 0, 0);
            acc1 = __builtin_amdgcn_mfma_f32_16x16x32_bf16(af1.v, q2.v, acc1, 0, 0, 0);
        }
        cA0a = nA0a; cA0b = nA0b; cA1a = nA1a; cA1b = nA1b;
    }

    // C/D layout (m89): col = l&15, row = 4*(l>>4) + reg. Rows are t.
    const int tt4_0 = ttbase + 4 * g;
    const int tt4_1 = tt4_0 + 16;
    if (r < C_OUT) {
        if (tt4_0 + 3 < cur) {
            const float4 v = make_float4(acc0[0], acc0[1], acc0[2], acc0[3]);
            *reinterpret_cast<float4*>(&Ibuf[((size_t)b * C_OUT + r) * cur + tt4_0]) = v;
        }
        if (tt4_1 + 3 < cur) {
            const float4 v = make_float4(acc1[0], acc1[1], acc1[2], acc1[3]);
            *reinterpret_cast<float4*>(&Ibuf[((size_t)b * C_OUT + r) * cur + tt4_1]) = v;
        }
    }
}

// ---------------------------------------------------------------------------
// Phase 2: per-neuron LIF scan, exact reference semantics (unchanged).
// ---------------------------------------------------------------------------
__device__ __forceinline__ void snn_step(float Iv, float& V, float& refr, float& cnt)
{
    const bool act = (refr <= 0.f);
    V += act ? Iv : 0.f;
    const bool fired = act && ((V - 0.4f) > 0.f);
    cnt += fired ? 1.f : 0.f;
    V    = fired ? 0.f : V;
    refr = fired ? 3.f : refr;
    refr = fmaxf(refr - 1.f, 0.f);
}

__global__ __launch_bounds__(256) void snn_phase2(
    const float* __restrict__ Ibuf, float* __restrict__ state,
    float* __restrict__ out, int t0, int Tc, int last)
{
    const int n = blockIdx.x * 256 + threadIdx.x;
    if (n >= NEUR) return;

    float V, refr, cnt;
    if (t0 == 0) { V = 0.f; refr = 0.f; cnt = 0.f; }
    else { V = state[n]; refr = state[NEUR + n]; cnt = state[2 * NEUR + n]; }

    const float* __restrict__ I = Ibuf + (size_t)n * Tc;

    int i = 0;
    for (; i + 16 <= Tc; i += 16) {
        const float4 a = *reinterpret_cast<const float4*>(I + i);
        const float4 b = *reinterpret_cast<const float4*>(I + i + 4);
        const float4 c = *reinterpret_cast<const float4*>(I + i + 8);
        const float4 d = *reinterpret_cast<const float4*>(I + i + 12);
        snn_step(a.x, V, refr, cnt); snn_step(a.y, V, refr, cnt);
        snn_step(a.z, V, refr, cnt); snn_step(a.w, V, refr, cnt);
        snn_step(b.x, V, refr, cnt); snn_step(b.y, V, refr, cnt);
        snn_step(b.z, V, refr, cnt); snn_step(b.w, V, refr, cnt);
        snn_step(c.x, V, refr, cnt); snn_step(c.y, V, refr, cnt);
        snn_step(c.z, V, refr, cnt); snn_step(c.w, V, refr, cnt);
        snn_step(d.x, V, refr, cnt); snn_step(d.y, V, refr, cnt);
        snn_step(d.z, V, refr, cnt); snn_step(d.w, V, refr, cnt);
    }
    for (; i < Tc; ++i) snn_step(I[i], V, refr, cnt);

    if (last) {
        out[n] = cnt;
    } else {
        state[n] = V; state[NEUR + n] = refr; state[2 * NEUR + n] = cnt;
    }
}

// ---------------------------------------------------------------------------
extern "C" void kernel_launch(void* const* d_in, const int* in_sizes, int n_in,
                              void* d_out, int out_size, void* d_ws, size_t ws_size,
                              hipStream_t stream)
{
    const float* x = (const float*)d_in[0];   // [128, 1000, 2048] fp32 {0,1}
    const float* W = (const float*)d_in[1];   // [2048, 10] fp32
    float* out = (float*)d_out;               // [128, 10] fp32

    // ws layout: state (15360 B) | bfrag (196608 B) | bits (32.768 MB) | Ibuf
    float* state = (float*)d_ws;
    uint4* bfrag = (uint4*)((char*)d_ws + 3 * NEUR * sizeof(float));
    uint4* bits  = (uint4*)((char*)d_ws + 3 * NEUR * sizeof(float) + NBFRAG * 16);
    float* Ibuf  = (float*)((char*)d_ws + 3 * NEUR * sizeof(float) + NBFRAG * 16
                            + (size_t)NBITU4 * 16);

    snn_prep<<<(NBFRAG + 255) / 256, 256, 0, stream>>>(W, bfrag);
    snn_compress<<<2048, 256, 0, stream>>>(x, bits);

    // Chunk T so Ibuf fits the workspace (single chunk at ws ~4 GB).
    const size_t head = 3 * NEUR + NBFRAG * 4 + (size_t)NBITU4 * 4;  // floats
    const size_t ws_floats = ws_size / sizeof(float);
    long avail = (long)ws_floats - (long)head;
    int Tc = (avail > 0) ? (int)(avail / NEUR) : 0;
    if (Tc > T_TOTAL) Tc = T_TOTAL;
    Tc &= ~3;
    if (Tc <= 0) Tc = 4;

    for (int t0 = 0; t0 < T_TOTAL; t0 += Tc) {
        int cur = T_TOTAL - t0; if (cur > Tc) cur = Tc;
        dim3 g1((cur + 127) / 128, B_TOTAL, 1);
        snn_phase1_bits<<<g1, 256, 0, stream>>>(bits, bfrag, Ibuf, t0, cur);
        const int last = (t0 + cur >= T_TOTAL) ? 1 : 0;
        snn_phase2<<<(NEUR + 255) / 256, 256, 0, stream>>>(Ibuf, state, out, t0, cur, last);
    }
}

// Round 4
// 290.607 us; speedup vs baseline: 1.0907x; 1.0441x over previous
//
#include <hip/hip_runtime.h>
#include <hip/hip_bf16.h>

#define T_TOTAL 1000
#define B_TOTAL 128
#define F_TOTAL 2048
#define C_OUT   10
#define NEUR    (B_TOTAL * C_OUT)   // 1280

#define KSTEPS  (F_TOTAL / 32)      // 64 k-steps of 32
#define NBFRAG  (KSTEPS * 3 * 64)   // 12288 16-byte B fragments (hi/mid/lo)

// bitmask geometry v2 (ballot-native): 256-elem group -> 32 B.
//   lane i of compress loads float4 (elems 4i..4i+3); w[c] = ballot(v[c]!=0)
//   => bit i of w[c] = x[G*256 + 4i + c].
//   stored: uint4 A = {w0.lo, w0.hi, w1.lo, w1.hi}, uint4 B = {w2.lo, w2.hi, w3.lo, w3.hi}
#define NELEM     (B_TOTAL * T_TOTAL * F_TOTAL)   // 262,144,000
#define NGROUP    (NELEM / 256)                   // 1,024,000 groups
#define NBITU4    (NGROUP * 2)                    // 2,048,000 uint4 = 32.768 MB
#define CITERS    (NGROUP / 4)                    // 256,000 wave-iters (4 groups each)

typedef __attribute__((ext_vector_type(8))) short bf16x8;
typedef __attribute__((ext_vector_type(4))) float f32x4;

// ---------------------------------------------------------------------------
// Prep: split W exactly into three bf16 terms (W == hi+mid+lo in fp32),
// frag-ordered: fragment idx = (s*3+p)*64 + lane, lane = 16g+r holds
// B[k = s*32 + 8g + j][col r], j=0..7 packed ascending.
// ---------------------------------------------------------------------------
__global__ __launch_bounds__(256) void snn_prep(const float* __restrict__ W,
                                                uint4* __restrict__ bfrag)
{
    const int idx = blockIdx.x * 256 + threadIdx.x;
    if (idx >= NBFRAG) return;
    const int l = idx & 63;
    const int sp = idx >> 6;
    const int p = sp % 3;            // split: 0=hi 1=mid 2=lo
    const int s = sp / 3;            // k-step
    const int g = l >> 4, r = l & 15;
    unsigned out[4] = {0u, 0u, 0u, 0u};
#pragma unroll
    for (int j = 0; j < 8; ++j) {
        const int k = s * 32 + g * 8 + j;
        const float wv = (r < C_OUT) ? W[k * C_OUT + r] : 0.f;
        __hip_bfloat16 bh = __float2bfloat16(wv);
        const float fh = __bfloat162float(bh);
        __hip_bfloat16 bm = __float2bfloat16(wv - fh);
        const float fm = __bfloat162float(bm);
        __hip_bfloat16 bl = __float2bfloat16(wv - fh - fm);   // exact residual
        __hip_bfloat16 sel = (p == 0) ? bh : (p == 1) ? bm : bl;
        const unsigned short bits = *reinterpret_cast<unsigned short*>(&sel);
        out[j >> 1] |= (unsigned)bits << (16 * (j & 1));
    }
    bfrag[idx] = make_uint4(out[0], out[1], out[2], out[3]);
}

// ---------------------------------------------------------------------------
// Compress v3: identical to v2 except the 1.05 GB x stream is read with
// NON-TEMPORAL loads (nt flag -> no L2/Infinity-Cache allocation). Theory:
// three different read patterns all plateaued ~4 TB/s while writes sustain
// 6.5 TB/s; candidate limiter is the cache-allocation fill path on reads.
// bits stores stay cached (phase1_bits wants them L2-resident).
// ---------------------------------------------------------------------------
__global__ __launch_bounds__(256) void snn_compress(const float* __restrict__ x,
                                                    uint4* __restrict__ bits)
{
    const int lane = threadIdx.x & 63;
    const int w    = threadIdx.x >> 6;
    const size_t wave_id = (size_t)blockIdx.x * 4 + w;
    const size_t nwaves  = (size_t)gridDim.x * 4;

    for (size_t it = wave_id; it < CITERS; it += nwaves) {
        const f32x4* __restrict__ p =
            reinterpret_cast<const f32x4*>(x + it * 1024 + 4 * lane);
        const f32x4 v0 = __builtin_nontemporal_load(p);
        const f32x4 v1 = __builtin_nontemporal_load(p + 64);   // +256 floats
        const f32x4 v2 = __builtin_nontemporal_load(p + 128);
        const f32x4 v3 = __builtin_nontemporal_load(p + 192);

        const unsigned long long b00 = __ballot(v0.x != 0.f);
        const unsigned long long b01 = __ballot(v0.y != 0.f);
        const unsigned long long b02 = __ballot(v0.z != 0.f);
        const unsigned long long b03 = __ballot(v0.w != 0.f);
        const unsigned long long b10 = __ballot(v1.x != 0.f);
        const unsigned long long b11 = __ballot(v1.y != 0.f);
        const unsigned long long b12 = __ballot(v1.z != 0.f);
        const unsigned long long b13 = __ballot(v1.w != 0.f);
        const unsigned long long b20 = __ballot(v2.x != 0.f);
        const unsigned long long b21 = __ballot(v2.y != 0.f);
        const unsigned long long b22 = __ballot(v2.z != 0.f);
        const unsigned long long b23 = __ballot(v2.w != 0.f);
        const unsigned long long b30 = __ballot(v3.x != 0.f);
        const unsigned long long b31 = __ballot(v3.y != 0.f);
        const unsigned long long b32 = __ballot(v3.z != 0.f);
        const unsigned long long b33 = __ballot(v3.w != 0.f);

        if (lane == 0) {
            uint4* __restrict__ o = bits + it * 8;
            o[0] = make_uint4((unsigned)b00, (unsigned)(b00 >> 32),
                              (unsigned)b01, (unsigned)(b01 >> 32));
            o[1] = make_uint4((unsigned)b02, (unsigned)(b02 >> 32),
                              (unsigned)b03, (unsigned)(b03 >> 32));
            o[2] = make_uint4((unsigned)b10, (unsigned)(b10 >> 32),
                              (unsigned)b11, (unsigned)(b11 >> 32));
            o[3] = make_uint4((unsigned)b12, (unsigned)(b12 >> 32),
                              (unsigned)b13, (unsigned)(b13 >> 32));
            o[4] = make_uint4((unsigned)b20, (unsigned)(b20 >> 32),
                              (unsigned)b21, (unsigned)(b21 >> 32));
            o[5] = make_uint4((unsigned)b22, (unsigned)(b22 >> 32),
                              (unsigned)b23, (unsigned)(b23 >> 32));
            o[6] = make_uint4((unsigned)b30, (unsigned)(b30 >> 32),
                              (unsigned)b31, (unsigned)(b31 >> 32));
            o[7] = make_uint4((unsigned)b32, (unsigned)(b32 >> 32),
                              (unsigned)b33, (unsigned)(b33 >> 32));
        }
    }
}

// ---------------------------------------------------------------------------
// Phase 1 (MFMA from bits v2). Per group (256 k, 8 k-steps), lane loads the
// row's 32 B {A,B} words. For step ss, lane (r,g), packed pair u[j]:
//   even elem = 32ss+8g+2j -> word w0 (j even) / w2 (j odd), bit 8(ss&3)+2g+(j>>1)
//   odd  elem = +1         -> word w1 (j even) / w3 (j odd), same bit
//   hi/lo u32 of the u64 selected by ss<4. Verified at corners (g,ss,j).
// ---------------------------------------------------------------------------
__device__ __forceinline__ unsigned sext_bit(unsigned wrd, int pos)
{
#if __has_builtin(__builtin_amdgcn_sbfe)
    return (unsigned)__builtin_amdgcn_sbfe((int)wrd, pos, 1);
#else
    return (unsigned)(((int)(wrd << (31 - pos))) >> 31);
#endif
}

#define EXPAND(Aa, Ab, AF)                                                        \
    {                                                                             \
        const unsigned w0 = (ss < 4) ? Aa.x : Aa.y;                               \
        const unsigned w1 = (ss < 4) ? Aa.z : Aa.w;                               \
        const unsigned w2 = (ss < 4) ? Ab.x : Ab.y;                               \
        const unsigned w3 = (ss < 4) ? Ab.z : Ab.w;                               \
        AF.u[0] = (sext_bit(w0, p0) & 0x3F80u) | (sext_bit(w1, p0) & 0x3F800000u); \
        AF.u[1] = (sext_bit(w2, p0) & 0x3F80u) | (sext_bit(w3, p0) & 0x3F800000u); \
        AF.u[2] = (sext_bit(w0, p1) & 0x3F80u) | (sext_bit(w1, p1) & 0x3F800000u); \
        AF.u[3] = (sext_bit(w2, p1) & 0x3F80u) | (sext_bit(w3, p1) & 0x3F800000u); \
    }

__global__ __launch_bounds__(256) void snn_phase1_bits(
    const uint4* __restrict__ bits, const uint4* __restrict__ bfrag,
    float* __restrict__ Ibuf, int t0, int cur)
{
    const int b  = blockIdx.y;
    const int w  = threadIdx.x >> 6;
    const int l  = threadIdx.x & 63;
    const int r  = l & 15, g = l >> 4;
    const int ttbase = blockIdx.x * 128 + w * 32;  // wave's 32-row tile (local t)

    int t_row0 = t0 + ttbase + r;
    int t_row1 = t_row0 + 16;
    if (t_row0 > T_TOTAL - 1) t_row0 = T_TOTAL - 1;
    if (t_row1 > T_TOTAL - 1) t_row1 = T_TOTAL - 1;
    // 8 groups per row (2048 elems) -> 16 uint4 per row.
    const uint4* __restrict__ ap0 = bits + (size_t)(b * T_TOTAL + t_row0) * 16;
    const uint4* __restrict__ ap1 = bits + (size_t)(b * T_TOTAL + t_row1) * 16;

    f32x4 acc0 = {0.f, 0.f, 0.f, 0.f};
    f32x4 acc1 = {0.f, 0.f, 0.f, 0.f};
    const uint4* __restrict__ bp = bfrag + l;

    const int g2 = 2 * g;            // per-lane bit-position base

    uint4 cA0a = ap0[0], cA0b = ap0[1];
    uint4 cA1a = ap1[0], cA1b = ap1[1];

#pragma unroll 1
    for (int gi = 0; gi < 8; ++gi) {
        // prefetch next group's words (clamped dup on last iter)
        const int gn = (gi < 7) ? gi + 1 : 7;
        const uint4 nA0a = ap0[gn * 2], nA0b = ap0[gn * 2 + 1];
        const uint4 nA1a = ap1[gn * 2], nA1b = ap1[gn * 2 + 1];

#pragma unroll
        for (int ss = 0; ss < 8; ++ss) {
            const int s = gi * 8 + ss;
            union { bf16x8 v; uint4 q; } q0, q1, q2;
            q0.q = bp[(s * 3 + 0) * 64];
            q1.q = bp[(s * 3 + 1) * 64];
            q2.q = bp[(s * 3 + 2) * 64];

            const int p0 = g2 + 8 * (ss & 3);   // compile-time const + 2g
            const int p1 = p0 + 1;

            union { bf16x8 v; unsigned u[4]; } af0, af1;
            EXPAND(cA0a, cA0b, af0)
            EXPAND(cA1a, cA1b, af1)

            acc0 = __builtin_amdgcn_mfma_f32_16x16x32_bf16(af0.v, q0.v, acc0, 0, 0, 0);
            acc1 = __builtin_amdgcn_mfma_f32_16x16x32_bf16(af1.v, q0.v, acc1, 0, 0, 0);
            acc0 = __builtin_amdgcn_mfma_f32_16x16x32_bf16(af0.v, q1.v, acc0, 0, 0, 0);
            acc1 = __builtin_amdgcn_mfma_f32_16x16x32_bf16(af1.v, q1.v, acc1, 0, 0, 0);
            acc0 = __builtin_amdgcn_mfma_f32_16x16x32_bf16(af0.v, q2.v, acc0, 0, 0, 0);
            acc1 = __builtin_amdgcn_mfma_f32_16x16x32_bf16(af1.v, q2.v, acc1, 0, 0, 0);
        }
        cA0a = nA0a; cA0b = nA0b; cA1a = nA1a; cA1b = nA1b;
    }

    // C/D layout (m89): col = l&15, row = 4*(l>>4) + reg. Rows are t.
    const int tt4_0 = ttbase + 4 * g;
    const int tt4_1 = tt4_0 + 16;
    if (r < C_OUT) {
        if (tt4_0 + 3 < cur) {
            const float4 v = make_float4(acc0[0], acc0[1], acc0[2], acc0[3]);
            *reinterpret_cast<float4*>(&Ibuf[((size_t)b * C_OUT + r) * cur + tt4_0]) = v;
        }
        if (tt4_1 + 3 < cur) {
            const float4 v = make_float4(acc1[0], acc1[1], acc1[2], acc1[3]);
            *reinterpret_cast<float4*>(&Ibuf[((size_t)b * C_OUT + r) * cur + tt4_1]) = v;
        }
    }
}

// ---------------------------------------------------------------------------
// Phase 2: per-neuron LIF scan, exact reference semantics (unchanged).
// ---------------------------------------------------------------------------
__device__ __forceinline__ void snn_step(float Iv, float& V, float& refr, float& cnt)
{
    const bool act = (refr <= 0.f);
    V += act ? Iv : 0.f;
    const bool fired = act && ((V - 0.4f) > 0.f);
    cnt += fired ? 1.f : 0.f;
    V    = fired ? 0.f : V;
    refr = fired ? 3.f : refr;
    refr = fmaxf(refr - 1.f, 0.f);
}

__global__ __launch_bounds__(256) void snn_phase2(
    const float* __restrict__ Ibuf, float* __restrict__ state,
    float* __restrict__ out, int t0, int Tc, int last)
{
    const int n = blockIdx.x * 256 + threadIdx.x;
    if (n >= NEUR) return;

    float V, refr, cnt;
    if (t0 == 0) { V = 0.f; refr = 0.f; cnt = 0.f; }
    else { V = state[n]; refr = state[NEUR + n]; cnt = state[2 * NEUR + n]; }

    const float* __restrict__ I = Ibuf + (size_t)n * Tc;

    int i = 0;
    for (; i + 16 <= Tc; i += 16) {
        const float4 a = *reinterpret_cast<const float4*>(I + i);
        const float4 b = *reinterpret_cast<const float4*>(I + i + 4);
        const float4 c = *reinterpret_cast<const float4*>(I + i + 8);
        const float4 d = *reinterpret_cast<const float4*>(I + i + 12);
        snn_step(a.x, V, refr, cnt); snn_step(a.y, V, refr, cnt);
        snn_step(a.z, V, refr, cnt); snn_step(a.w, V, refr, cnt);
        snn_step(b.x, V, refr, cnt); snn_step(b.y, V, refr, cnt);
        snn_step(b.z, V, refr, cnt); snn_step(b.w, V, refr, cnt);
        snn_step(c.x, V, refr, cnt); snn_step(c.y, V, refr, cnt);
        snn_step(c.z, V, refr, cnt); snn_step(c.w, V, refr, cnt);
        snn_step(d.x, V, refr, cnt); snn_step(d.y, V, refr, cnt);
        snn_step(d.z, V, refr, cnt); snn_step(d.w, V, refr, cnt);
    }
    for (; i < Tc; ++i) snn_step(I[i], V, refr, cnt);

    if (last) {
        out[n] = cnt;
    } else {
        state[n] = V; state[NEUR + n] = refr; state[2 * NEUR + n] = cnt;
    }
}

// ---------------------------------------------------------------------------
extern "C" void kernel_launch(void* const* d_in, const int* in_sizes, int n_in,
                              void* d_out, int out_size, void* d_ws, size_t ws_size,
                              hipStream_t stream)
{
    const float* x = (const float*)d_in[0];   // [128, 1000, 2048] fp32 {0,1}
    const float* W = (const float*)d_in[1];   // [2048, 10] fp32
    float* out = (float*)d_out;               // [128, 10] fp32

    // ws layout: state (15360 B) | bfrag (196608 B) | bits (32.768 MB) | Ibuf
    float* state = (float*)d_ws;
    uint4* bfrag = (uint4*)((char*)d_ws + 3 * NEUR * sizeof(float));
    uint4* bits  = (uint4*)((char*)d_ws + 3 * NEUR * sizeof(float) + NBFRAG * 16);
    float* Ibuf  = (float*)((char*)d_ws + 3 * NEUR * sizeof(float) + NBFRAG * 16
                            + (size_t)NBITU4 * 16);

    snn_prep<<<(NBFRAG + 255) / 256, 256, 0, stream>>>(W, bfrag);
    snn_compress<<<2048, 256, 0, stream>>>(x, bits);

    // Chunk T so Ibuf fits the workspace (single chunk at ws ~4 GB).
    const size_t head = 3 * NEUR + NBFRAG * 4 + (size_t)NBITU4 * 4;  // floats
    const size_t ws_floats = ws_size / sizeof(float);
    long avail = (long)ws_floats - (long)head;
    int Tc = (avail > 0) ? (int)(avail / NEUR) : 0;
    if (Tc > T_TOTAL) Tc = T_TOTAL;
    Tc &= ~3;
    if (Tc <= 0) Tc = 4;

    for (int t0 = 0; t0 < T_TOTAL; t0 += Tc) {
        int cur = T_TOTAL - t0; if (cur > Tc) cur = Tc;
        dim3 g1((cur + 127) / 128, B_TOTAL, 1);
        snn_phase1_bits<<<g1, 256, 0, stream>>>(bits, bfrag, Ibuf, t0, cur);
        const int last = (t0 + cur >= T_TOTAL) ? 1 : 0;
        snn_phase2<<<(NEUR + 255) / 256, 256, 0, stream>>>(Ibuf, state, out, t0, cur, last);
    }
}